// Round 13
// baseline (46.443 us; speedup 1.0000x reference)
//
#include <hip/hip_runtime.h>
#include <hip/hip_bf16.h>
#include <math.h>

typedef short short8 __attribute__((ext_vector_type(8)));
typedef float f32x4 __attribute__((ext_vector_type(4)));

#define NQ 32
#define NDOCS 8
#define QLEN 32
#define DLEN 200
#define DIM 128
#define MD 256            // total docs
#define HD_ROWS 208       // 200 real + 8 zero pad rows
#define DOC_SHORTS (HD_ROWS * DIM)      // 26624 bf16 = 53248 B per doc
#define DOC_BYTES (DOC_SHORTS * 2)      // 53248
#define DOC_CHUNKS (HD_ROWS * 16)       // 3328 16B-chunks per doc

__device__ __forceinline__ short f2bf(float x) {
    union { float f; unsigned u; } v; v.f = x;
    unsigned r = v.u + 0x7FFFu + ((v.u >> 16) & 1u);  // RNE
    return (short)(r >> 16);
}

__device__ __forceinline__ short8 cvt8(float4 f0, float4 f1) {
    short8 o;
    o[0] = f2bf(f0.x); o[1] = f2bf(f0.y); o[2] = f2bf(f0.z); o[3] = f2bf(f0.w);
    o[4] = f2bf(f1.x); o[5] = f2bf(f1.y); o[6] = f2bf(f1.z); o[7] = f2bf(f1.w);
    return o;
}

// hd fp32 -> bf16, PRE-SWIZZLED in global (chunk kc -> kc ^ (row&7) within each row),
// pad rows 200..207 zeroed. Scores kernel copies linearly into LDS (global_load_lds)
// and applies the XOR on ds_read (swizzle source + read, LDS dest linear).
__global__ __launch_bounds__(256) void convert_hd(const float* __restrict__ hd,
                                                  short* __restrict__ hdb) {
    unsigned c = blockIdx.x * 256 + threadIdx.x;       // global chunk id, < 851968
    unsigned m = c / DOC_CHUNKS;
    unsigned rc = c - m * DOC_CHUNKS;
    unsigned row = rc >> 4, kc = rc & 15;
    short8 o = {0, 0, 0, 0, 0, 0, 0, 0};
    if (row < DLEN) {
        const float4* p = reinterpret_cast<const float4*>(
            hd + ((size_t)m * DLEN + row) * DIM + kc * 8);
        o = cvt8(p[0], p[1]);
    }
    unsigned dst = m * DOC_CHUNKS + row * 16 + (kc ^ (row & 7));
    reinterpret_cast<short8*>(hdb)[dst] = o;
}

// grid = 512: b = qh*256 + m (b%8 = m%8 -> both blocks of doc m on one XCD).
// Block: 512 thr / 8 waves, LDS 53KB -> 2 blocks/CU. Wave wid: questions
// n0 = qh*16 + wid*2 + {0,1}  -> Bq 64 VGPR, 4 MFMA per ds_read_b128 (2x R12 ratio).
// KEY: __launch_bounds__(512, 2) relaxes VGPR cap to 256 (R6/R11 evidence) -> no spill.
// C = mfma(A=hd_frag, B=hq_frag): lane holds C[d = dt*16 + lg*4 + r][q = qt*16 + lr].
__global__ __launch_bounds__(512, 2) void colbert_scores(const float* __restrict__ hq,
                                                         const short* __restrict__ hdb,
                                                         float* __restrict__ out) {
    __shared__ char lds[DOC_BYTES];   // 53248 B
    const int tid = threadIdx.x;
    const int b = blockIdx.x;
    const int m = b & 255, qh = b >> 8;
    const int wid = tid >> 6, lane = tid & 63;
    const int lg = lane >> 4, lr = lane & 15;
    const int n0 = qh * 16 + wid * 2;

    // ---- 1) stage doc m via direct HBM/L2 -> LDS DMA (no staging VGPRs) ----
    const char* gsrc = reinterpret_cast<const char*>(hdb + (size_t)m * DOC_SHORTS);
    {
        const int lbase = wid * 1024;            // wave-uniform LDS base
        const int gbase = lbase + lane * 16;     // per-lane global address
        #pragma unroll
        for (int i = 0; i < 6; ++i)
            __builtin_amdgcn_global_load_lds(
                (const __attribute__((address_space(1))) void*)(gsrc + i * 8192 + gbase),
                (__attribute__((address_space(3))) void*)(lds + i * 8192 + lbase),
                16, 0, 0);
        if (wid < 4)   // last 4KB: chunks 3072..3327
            __builtin_amdgcn_global_load_lds(
                (const __attribute__((address_space(1))) void*)(gsrc + 49152 + gbase),
                (__attribute__((address_space(3))) void*)(lds + 49152 + lbase),
                16, 0, 0);
    }

    // ---- 2) Bq for 2 questions (fp32 -> bf16 inline), overlapped with staging ----
    short8 Bq[2][2][4];
    #pragma unroll
    for (int nn = 0; nn < 2; ++nn)
        #pragma unroll
        for (int qt = 0; qt < 2; ++qt)
            #pragma unroll
            for (int s = 0; s < 4; ++s) {
                const float4* p = reinterpret_cast<const float4*>(
                    hq + (size_t)((n0 + nn) * QLEN + qt * 16 + lr) * DIM + s * 32 + lg * 8);
                Bq[nn][qt][s] = cvt8(p[0], p[1]);
            }

    __syncthreads();   // drains vmcnt (incl. global_load_lds) + barrier

    // ---- 3) compute: 13 tiles x (4 ds_read_b128 + 16 MFMA) ----
    int va[4];
    #pragma unroll
    for (int s = 0; s < 4; ++s)
        va[s] = lr * 256 + ((s * 64 + lg * 16) ^ ((lr & 7) << 4));

    float qmax[2][2];
    #pragma unroll
    for (int nn = 0; nn < 2; ++nn)
        #pragma unroll
        for (int qt = 0; qt < 2; ++qt) qmax[nn][qt] = -INFINITY;

#define STEP(DT, MASKED)                                                          \
    {                                                                             \
        f32x4 a00 = {0,0,0,0}, a01 = {0,0,0,0}, a10 = {0,0,0,0}, a11 = {0,0,0,0}; \
        __builtin_amdgcn_s_setprio(1);                                            \
        _Pragma("unroll")                                                         \
        for (int s = 0; s < 4; ++s) {                                             \
            short8 A_ = *reinterpret_cast<const short8*>(&lds[va[s] + (DT) * 4096]); \
            a00 = __builtin_amdgcn_mfma_f32_16x16x32_bf16(A_, Bq[0][0][s], a00, 0, 0, 0); \
            a01 = __builtin_amdgcn_mfma_f32_16x16x32_bf16(A_, Bq[0][1][s], a01, 0, 0, 0); \
            a10 = __builtin_amdgcn_mfma_f32_16x16x32_bf16(A_, Bq[1][0][s], a10, 0, 0, 0); \
            a11 = __builtin_amdgcn_mfma_f32_16x16x32_bf16(A_, Bq[1][1][s], a11, 0, 0, 0); \
        }                                                                         \
        __builtin_amdgcn_s_setprio(0);                                            \
        if (!(MASKED) || lg < 2) {                                                \
            qmax[0][0] = fmaxf(qmax[0][0], fmaxf(fmaxf(a00[0], a00[1]), fmaxf(a00[2], a00[3]))); \
            qmax[0][1] = fmaxf(qmax[0][1], fmaxf(fmaxf(a01[0], a01[1]), fmaxf(a01[2], a01[3]))); \
            qmax[1][0] = fmaxf(qmax[1][0], fmaxf(fmaxf(a10[0], a10[1]), fmaxf(a10[2], a10[3]))); \
            qmax[1][1] = fmaxf(qmax[1][1], fmaxf(fmaxf(a11[0], a11[1]), fmaxf(a11[2], a11[3]))); \
        }                                                                         \
    }

    #pragma unroll
    for (int dt = 0; dt < 12; ++dt) STEP(dt, false);
    STEP(12, true);   // rows 192..199 valid only for lg<2 (200..207 are zero pad)
#undef STEP

    // max over d: combine the 4 lg groups (lanes ^16, ^32)
    #pragma unroll
    for (int off = 16; off <= 32; off <<= 1)
        #pragma unroll
        for (int nn = 0; nn < 2; ++nn)
            #pragma unroll
            for (int qt = 0; qt < 2; ++qt)
                qmax[nn][qt] = fmaxf(qmax[nn][qt], __shfl_xor(qmax[nn][qt], off, 64));

    // mean over q-tokens: lane lr holds tokens lr and 16+lr; sum across the 16 lr lanes
    float s0 = qmax[0][0] + qmax[0][1];
    float s1 = qmax[1][0] + qmax[1][1];
    #pragma unroll
    for (int off = 1; off <= 8; off <<= 1) {
        s0 += __shfl_xor(s0, off, 64);
        s1 += __shfl_xor(s1, off, 64);
    }
    if (lane == 0) {
        out[(size_t)n0 * MD + m] = s0 * (1.0f / 32.0f);
        out[(size_t)(n0 + 1) * MD + m] = s1 * (1.0f / 32.0f);
    }
}

// loss = mean_n( logsumexp(row_n) - row_n[8n] )
__global__ __launch_bounds__(256) void colbert_loss(const float* __restrict__ scores,
                                                    float* __restrict__ loss_out) {
    __shared__ float terms[NQ];
    const int tid = threadIdx.x;
    const int wid = tid >> 6, lane = tid & 63;
    for (int n = wid; n < NQ; n += 4) {
        const float* row = scores + n * MD;
        float v0 = row[lane], v1 = row[64 + lane], v2 = row[128 + lane], v3 = row[192 + lane];
        float mx = fmaxf(fmaxf(v0, v1), fmaxf(v2, v3));
        #pragma unroll
        for (int off = 1; off < 64; off <<= 1) mx = fmaxf(mx, __shfl_xor(mx, off, 64));
        float s = expf(v0 - mx) + expf(v1 - mx) + expf(v2 - mx) + expf(v3 - mx);
        #pragma unroll
        for (int off = 1; off < 64; off <<= 1) s += __shfl_xor(s, off, 64);
        if (lane == 0) terms[n] = (mx + logf(s)) - row[n * NDOCS];
    }
    __syncthreads();
    if (tid == 0) {
        float acc = 0.f;
        #pragma unroll
        for (int n = 0; n < NQ; ++n) acc += terms[n];
        loss_out[0] = acc * (1.0f / NQ);
    }
}

extern "C" void kernel_launch(void* const* d_in, const int* in_sizes, int n_in,
                              void* d_out, int out_size, void* d_ws, size_t ws_size,
                              hipStream_t stream) {
    const float* hq = (const float*)d_in[0];   // [32][32][128] f32
    const float* hd = (const float*)d_in[1];   // [256][200][128] f32
    float* out = (float*)d_out;                // 8192 scores + 1 loss
    short* hdb = (short*)d_ws;                 // 256 docs x 208 rows x 128 bf16 (pre-swizzled)

    convert_hd<<<3328, 256, 0, stream>>>(hd, hdb);
    colbert_scores<<<512, 512, 0, stream>>>(hq, hdb, out);
    colbert_loss<<<1, 256, 0, stream>>>(out, out + NQ * MD);
}

// Round 14
// 41.642 us; speedup vs baseline: 1.1153x; 1.1153x over previous
//
#include <hip/hip_runtime.h>
#include <hip/hip_bf16.h>
#include <math.h>

typedef short short8 __attribute__((ext_vector_type(8)));
typedef float f32x4 __attribute__((ext_vector_type(4)));

#define NQ 32
#define NDOCS 8
#define QLEN 32
#define DLEN 200
#define DIM 128
#define MD 256            // total docs
#define HD_ROWS 208       // 200 real + 8 zero pad rows
#define DOC_SHORTS (HD_ROWS * DIM)      // 26624 bf16 = 53248 B per doc
#define DOC_BYTES (DOC_SHORTS * 2)      // 53248
#define DOC_CHUNKS (HD_ROWS * 16)       // 3328 16B-chunks per doc

__device__ __forceinline__ short f2bf(float x) {
    union { float f; unsigned u; } v; v.f = x;
    unsigned r = v.u + 0x7FFFu + ((v.u >> 16) & 1u);  // RNE
    return (short)(r >> 16);
}

__device__ __forceinline__ short8 cvt8(float4 f0, float4 f1) {
    short8 o;
    o[0] = f2bf(f0.x); o[1] = f2bf(f0.y); o[2] = f2bf(f0.z); o[3] = f2bf(f0.w);
    o[4] = f2bf(f1.x); o[5] = f2bf(f1.y); o[6] = f2bf(f1.z); o[7] = f2bf(f1.w);
    return o;
}

// hd fp32 -> bf16, PRE-SWIZZLED (chunk kc -> kc ^ (row&7)), pad rows zeroed,
// XCD-AFFINE: block class x=b&7 converts docs m with m%8==x, so doc data is
// written through the same XCD's L2 that the scores block (b%8==m%8) reads.
__global__ __launch_bounds__(256) void convert_hd(const float* __restrict__ hd,
                                                  short* __restrict__ hdb) {
    const unsigned b = blockIdx.x;                 // 3328 blocks
    const unsigned x = b & 7, g = b >> 3;          // g in 0..415
    unsigned idx = g * 256 + threadIdx.x;          // chunk idx within class x
    unsigned dc = idx / DOC_CHUNKS;                // doc within class: 0..31
    unsigned rc = idx - dc * DOC_CHUNKS;
    unsigned m = dc * 8 + x;
    unsigned row = rc >> 4, kc = rc & 15;
    short8 o = {0, 0, 0, 0, 0, 0, 0, 0};
    if (row < DLEN) {
        const float4* p = reinterpret_cast<const float4*>(
            hd + ((size_t)m * DLEN + row) * DIM + kc * 8);
        o = cvt8(p[0], p[1]);
    }
    unsigned dst = m * DOC_CHUNKS + row * 16 + (kc ^ (row & 7));
    reinterpret_cast<short8*>(hdb)[dst] = o;
}

// R9 structure + T3/T4 phased staging. grid = 2048: b = qg*256 + m.
// Block: 256 thr / 4 waves, LDS 53KB -> 3 blocks/CU. Wave wid: question n = qg*4+wid
// (one question/wave: live ~55 VGPR -> no spill at the compiler's 64-cap).
// Pipeline per block: [Bq loads] [stage 0..7] vmcnt(4)+bar [stage 8..12]
// [compute t0..3] vmcnt(5)+bar [compute t4..7] vmcnt(0)+bar [compute t8..12].
// vmcnt waits release the OLDEST ops (m135), so counts are exact per wave.
// C = mfma(A=hd_frag, B=hq_frag): lane holds C[d = dt*16 + lg*4 + r][q = qt*16 + lr].
__global__ __launch_bounds__(256) void colbert_scores(const float* __restrict__ hq,
                                                      const short* __restrict__ hdb,
                                                      float* __restrict__ out) {
    __shared__ char lds[DOC_BYTES];   // 53248 B
    const int tid = threadIdx.x;
    const int b = blockIdx.x;
    const int m = b & 255, qg = b >> 8;
    const int wid = tid >> 6, lane = tid & 63;
    const int lg = lane >> 4, lr = lane & 15;
    const int n = qg * 4 + wid;

    // ---- Bq loads FIRST (oldest in vmcnt order, so stage waits don't drain them) ----
    short8 Bq[2][4];
    #pragma unroll
    for (int qt = 0; qt < 2; ++qt)
        #pragma unroll
        for (int s = 0; s < 4; ++s) {
            const float4* p = reinterpret_cast<const float4*>(
                hq + (size_t)(n * QLEN + qt * 16 + lr) * DIM + s * 32 + lg * 8);
            Bq[qt][s] = cvt8(p[0], p[1]);
        }

    // ---- stage phase A+B: sweeps 0..7 (4 KB each, lane*16 within sweep) ----
    const char* gsrc = reinterpret_cast<const char*>(hdb) + (size_t)m * DOC_BYTES;
    const int goff = wid * 1024 + lane * 16;
    const int lbase = wid * 1024;
    #pragma unroll
    for (int i = 0; i < 8; ++i)
        __builtin_amdgcn_global_load_lds(
            (const __attribute__((address_space(1))) void*)(gsrc + i * 4096 + goff),
            (__attribute__((address_space(3))) void*)(lds + i * 4096 + lbase),
            16, 0, 0);

    asm volatile("s_waitcnt vmcnt(4)" ::: "memory");   // sweeps 0..3 landed (B in flight)
    __builtin_amdgcn_s_barrier();
    __builtin_amdgcn_sched_barrier(0);

    // ---- stage phase C: sweeps 8..12 (in flight under compute of tiles 0..3) ----
    #pragma unroll
    for (int i = 8; i < 13; ++i)
        __builtin_amdgcn_global_load_lds(
            (const __attribute__((address_space(1))) void*)(gsrc + i * 4096 + goff),
            (__attribute__((address_space(3))) void*)(lds + i * 4096 + lbase),
            16, 0, 0);

    int va[4];
    #pragma unroll
    for (int s = 0; s < 4; ++s)
        va[s] = lr * 256 + ((s * 64 + lg * 16) ^ ((lr & 7) << 4));

    float qmax0 = -INFINITY, qmax1 = -INFINITY;

#define STEP(DT, MASKED)                                                          \
    {                                                                             \
        f32x4 a0 = {0.f, 0.f, 0.f, 0.f}, a1 = {0.f, 0.f, 0.f, 0.f};               \
        _Pragma("unroll")                                                         \
        for (int s = 0; s < 4; ++s) {                                             \
            short8 A_ = *reinterpret_cast<const short8*>(&lds[va[s] + (DT) * 4096]); \
            a0 = __builtin_amdgcn_mfma_f32_16x16x32_bf16(A_, Bq[0][s], a0, 0, 0, 0); \
            a1 = __builtin_amdgcn_mfma_f32_16x16x32_bf16(A_, Bq[1][s], a1, 0, 0, 0); \
        }                                                                         \
        if (!(MASKED) || lg < 2) {                                                \
            qmax0 = fmaxf(qmax0, fmaxf(fmaxf(a0[0], a0[1]), fmaxf(a0[2], a0[3])));\
            qmax1 = fmaxf(qmax1, fmaxf(fmaxf(a1[0], a1[1]), fmaxf(a1[2], a1[3])));\
        }                                                                         \
    }

    // compute tiles 0..3 (sweeps 4..12 still arriving)
    #pragma unroll
    for (int dt = 0; dt < 4; ++dt) STEP(dt, false);

    asm volatile("s_waitcnt vmcnt(5)" ::: "memory");   // sweeps 4..7 landed (C in flight)
    __builtin_amdgcn_s_barrier();
    __builtin_amdgcn_sched_barrier(0);

    #pragma unroll
    for (int dt = 4; dt < 8; ++dt) STEP(dt, false);

    asm volatile("s_waitcnt vmcnt(0)" ::: "memory");   // sweeps 8..12 landed
    __builtin_amdgcn_s_barrier();
    __builtin_amdgcn_sched_barrier(0);

    #pragma unroll
    for (int dt = 8; dt < 12; ++dt) STEP(dt, false);
    STEP(12, true);   // rows 192..199 valid only for lg<2 (200..207 are zero pad)
#undef STEP

    // max over d: combine the 4 lg groups (lanes ^16, ^32)
    #pragma unroll
    for (int off = 16; off <= 32; off <<= 1) {
        qmax0 = fmaxf(qmax0, __shfl_xor(qmax0, off, 64));
        qmax1 = fmaxf(qmax1, __shfl_xor(qmax1, off, 64));
    }
    // mean over q-tokens: lane lr holds tokens lr and 16+lr; sum across the 16 lr lanes
    float s = qmax0 + qmax1;
    #pragma unroll
    for (int off = 1; off <= 8; off <<= 1) s += __shfl_xor(s, off, 64);
    if (lane == 0) out[(size_t)n * MD + m] = s * (1.0f / 32.0f);
}

// loss = mean_n( logsumexp(row_n) - row_n[8n] )
__global__ __launch_bounds__(256) void colbert_loss(const float* __restrict__ scores,
                                                    float* __restrict__ loss_out) {
    __shared__ float terms[NQ];
    const int tid = threadIdx.x;
    const int wid = tid >> 6, lane = tid & 63;
    for (int n = wid; n < NQ; n += 4) {
        const float* row = scores + n * MD;
        float v0 = row[lane], v1 = row[64 + lane], v2 = row[128 + lane], v3 = row[192 + lane];
        float mx = fmaxf(fmaxf(v0, v1), fmaxf(v2, v3));
        #pragma unroll
        for (int off = 1; off < 64; off <<= 1) mx = fmaxf(mx, __shfl_xor(mx, off, 64));
        float s = expf(v0 - mx) + expf(v1 - mx) + expf(v2 - mx) + expf(v3 - mx);
        #pragma unroll
        for (int off = 1; off < 64; off <<= 1) s += __shfl_xor(s, off, 64);
        if (lane == 0) terms[n] = (mx + logf(s)) - row[n * NDOCS];
    }
    __syncthreads();
    if (tid == 0) {
        float acc = 0.f;
        #pragma unroll
        for (int n = 0; n < NQ; ++n) acc += terms[n];
        loss_out[0] = acc * (1.0f / NQ);
    }
}

extern "C" void kernel_launch(void* const* d_in, const int* in_sizes, int n_in,
                              void* d_out, int out_size, void* d_ws, size_t ws_size,
                              hipStream_t stream) {
    const float* hq = (const float*)d_in[0];   // [32][32][128] f32
    const float* hd = (const float*)d_in[1];   // [256][200][128] f32
    float* out = (float*)d_out;                // 8192 scores + 1 loss
    short* hdb = (short*)d_ws;                 // 256 docs x 208 rows x 128 bf16 (pre-swizzled)

    convert_hd<<<3328, 256, 0, stream>>>(hd, hdb);
    colbert_scores<<<2048, 256, 0, stream>>>(hq, hdb, out);
    colbert_loss<<<1, 256, 0, stream>>>(out, out + NQ * MD);
}

// Round 15
// 39.712 us; speedup vs baseline: 1.1695x; 1.0486x over previous
//
#include <hip/hip_runtime.h>
#include <hip/hip_bf16.h>
#include <math.h>

typedef short short8 __attribute__((ext_vector_type(8)));
typedef float f32x4 __attribute__((ext_vector_type(4)));

#define NQ 32
#define NDOCS 8
#define QLEN 32
#define DLEN 200
#define DIM 128
#define MD 256            // total docs
#define ROWB 256          // LDS row stride bytes (128 bf16)

__device__ __forceinline__ short f2bf(float x) {
    union { float f; unsigned u; } v; v.f = x;
    unsigned r = v.u + 0x7FFFu + ((v.u >> 16) & 1u);  // RNE
    return (short)(r >> 16);
}

__device__ __forceinline__ short8 cvt8(float4 f0, float4 f1) {
    short8 o;
    o[0] = f2bf(f0.x); o[1] = f2bf(f0.y); o[2] = f2bf(f0.z); o[3] = f2bf(f0.w);
    o[4] = f2bf(f1.x); o[5] = f2bf(f1.y); o[6] = f2bf(f1.z); o[7] = f2bf(f1.w);
    return o;
}

// chunk c (8 bf16): row=c>>4, kc=c&15; XOR-swizzled LDS write (verified R3/R10)
__device__ __forceinline__ void writeChunk(char* lds, int c, float4 f0, float4 f1) {
    int row = c >> 4, kc = c & 15;
    int byte = row * ROWB + ((kc * 16) ^ ((row & 7) << 4));
    *reinterpret_cast<short8*>(&lds[byte]) = cvt8(f0, f1);
}

// grid = 1024: b = qo*256 + m (b%8 = m%8 -> all 4 blocks of doc m on one XCD).
// Block: 256 thr / 4 waves, LDS 53KB -> 3 blocks/CU. Wave wid: questions
// n = qo*8 + wid*2 + {0,1} -> Bq 64 VGPR, 4 MFMA per ds_read_b128 (halved LDS reads).
// __launch_bounds__(256,2): the ONLY proven spill-safe shape (R6/R11) -> cap 256 VGPR.
// No convert pass: fp32 hd staged+converted in-kernel; hd read exactly once from HBM.
// C = mfma(A=hd_frag, B=hq_frag): lane holds C[d = dt*16 + lg*4 + r][q = qt*16 + lr].
__global__ __launch_bounds__(256, 2) void colbert_scores(const float* __restrict__ hq,
                                                         const float* __restrict__ hd,
                                                         float* __restrict__ out) {
    __shared__ char lds[208 * ROWB];   // 53248 B (rows 200..207 junk; masked)
    const int tid = threadIdx.x;
    const int b = blockIdx.x;
    const int m = b & 255, qo = b >> 8;
    const int wid = tid >> 6, lane = tid & 63;
    const int lg = lane >> 4, lr = lane & 15;
    const int n0 = qo * 8 + wid * 2;

    // ---- stage doc m: fp32 -> bf16 -> swizzled LDS (3200 chunks of 8 elems) ----
    const float4* src4 = reinterpret_cast<const float4*>(hd + (size_t)m * (DLEN * DIM));
    #pragma unroll
    for (int i = 0; i < 12; ++i) {
        int c = tid + i * 256;
        float4 f0 = src4[c * 2], f1 = src4[c * 2 + 1];
        writeChunk(lds, c, f0, f1);
    }
    if (tid < 128) {
        int c = 3072 + tid;
        float4 f0 = src4[c * 2], f1 = src4[c * 2 + 1];
        writeChunk(lds, c, f0, f1);
    }

    // ---- Bq for 2 questions (fp32 -> bf16 inline): 64 VGPR held ----
    short8 Bq[2][2][4];
    #pragma unroll
    for (int nn = 0; nn < 2; ++nn)
        #pragma unroll
        for (int qt = 0; qt < 2; ++qt)
            #pragma unroll
            for (int s = 0; s < 4; ++s) {
                const float4* p = reinterpret_cast<const float4*>(
                    hq + (size_t)((n0 + nn) * QLEN + qt * 16 + lr) * DIM + s * 32 + lg * 8);
                Bq[nn][qt][s] = cvt8(p[0], p[1]);
            }

    __syncthreads();

    // ---- compute: 13 tiles x (4 ds_read_b128 + 16 MFMA) ----
    int va[4];
    #pragma unroll
    for (int s = 0; s < 4; ++s)
        va[s] = lr * ROWB + ((s * 64 + lg * 16) ^ ((lr & 7) << 4));

    float qmax[2][2];
    #pragma unroll
    for (int nn = 0; nn < 2; ++nn)
        #pragma unroll
        for (int qt = 0; qt < 2; ++qt) qmax[nn][qt] = -INFINITY;

#define STEP(DT, MASKED)                                                          \
    {                                                                             \
        f32x4 a00 = {0,0,0,0}, a01 = {0,0,0,0}, a10 = {0,0,0,0}, a11 = {0,0,0,0}; \
        _Pragma("unroll")                                                         \
        for (int s = 0; s < 4; ++s) {                                             \
            short8 A_ = *reinterpret_cast<const short8*>(&lds[va[s] + (DT) * 4096]); \
            a00 = __builtin_amdgcn_mfma_f32_16x16x32_bf16(A_, Bq[0][0][s], a00, 0, 0, 0); \
            a01 = __builtin_amdgcn_mfma_f32_16x16x32_bf16(A_, Bq[0][1][s], a01, 0, 0, 0); \
            a10 = __builtin_amdgcn_mfma_f32_16x16x32_bf16(A_, Bq[1][0][s], a10, 0, 0, 0); \
            a11 = __builtin_amdgcn_mfma_f32_16x16x32_bf16(A_, Bq[1][1][s], a11, 0, 0, 0); \
        }                                                                         \
        if (!(MASKED) || lg < 2) {                                                \
            qmax[0][0] = fmaxf(qmax[0][0], fmaxf(fmaxf(a00[0], a00[1]), fmaxf(a00[2], a00[3]))); \
            qmax[0][1] = fmaxf(qmax[0][1], fmaxf(fmaxf(a01[0], a01[1]), fmaxf(a01[2], a01[3]))); \
            qmax[1][0] = fmaxf(qmax[1][0], fmaxf(fmaxf(a10[0], a10[1]), fmaxf(a10[2], a10[3]))); \
            qmax[1][1] = fmaxf(qmax[1][1], fmaxf(fmaxf(a11[0], a11[1]), fmaxf(a11[2], a11[3]))); \
        }                                                                         \
    }

    #pragma unroll
    for (int dt = 0; dt < 12; ++dt) STEP(dt, false);
    STEP(12, true);   // rows 192..199 valid only for lg<2 (200..207 junk, masked)
#undef STEP

    // max over d: combine the 4 lg groups (lanes ^16, ^32)
    #pragma unroll
    for (int off = 16; off <= 32; off <<= 1)
        #pragma unroll
        for (int nn = 0; nn < 2; ++nn)
            #pragma unroll
            for (int qt = 0; qt < 2; ++qt)
                qmax[nn][qt] = fmaxf(qmax[nn][qt], __shfl_xor(qmax[nn][qt], off, 64));

    // mean over q-tokens: lane lr holds tokens lr and 16+lr; sum across the 16 lr lanes
    float s0 = qmax[0][0] + qmax[0][1];
    float s1 = qmax[1][0] + qmax[1][1];
    #pragma unroll
    for (int off = 1; off <= 8; off <<= 1) {
        s0 += __shfl_xor(s0, off, 64);
        s1 += __shfl_xor(s1, off, 64);
    }
    if (lane == 0) {
        out[(size_t)n0 * MD + m] = s0 * (1.0f / 32.0f);
        out[(size_t)(n0 + 1) * MD + m] = s1 * (1.0f / 32.0f);
    }
}

// loss = mean_n( logsumexp(row_n) - row_n[8n] )
__global__ __launch_bounds__(256) void colbert_loss(const float* __restrict__ scores,
                                                    float* __restrict__ loss_out) {
    __shared__ float terms[NQ];
    const int tid = threadIdx.x;
    const int wid = tid >> 6, lane = tid & 63;
    for (int n = wid; n < NQ; n += 4) {
        const float* row = scores + n * MD;
        float v0 = row[lane], v1 = row[64 + lane], v2 = row[128 + lane], v3 = row[192 + lane];
        float mx = fmaxf(fmaxf(v0, v1), fmaxf(v2, v3));
        #pragma unroll
        for (int off = 1; off < 64; off <<= 1) mx = fmaxf(mx, __shfl_xor(mx, off, 64));
        float s = expf(v0 - mx) + expf(v1 - mx) + expf(v2 - mx) + expf(v3 - mx);
        #pragma unroll
        for (int off = 1; off < 64; off <<= 1) s += __shfl_xor(s, off, 64);
        if (lane == 0) terms[n] = (mx + logf(s)) - row[n * NDOCS];
    }
    __syncthreads();
    if (tid == 0) {
        float acc = 0.f;
        #pragma unroll
        for (int n = 0; n < NQ; ++n) acc += terms[n];
        loss_out[0] = acc * (1.0f / NQ);
    }
}

extern "C" void kernel_launch(void* const* d_in, const int* in_sizes, int n_in,
                              void* d_out, int out_size, void* d_ws, size_t ws_size,
                              hipStream_t stream) {
    const float* hq = (const float*)d_in[0];   // [32][32][128] f32
    const float* hd = (const float*)d_in[1];   // [256][200][128] f32
    float* out = (float*)d_out;                // 8192 scores + 1 loss

    colbert_scores<<<1024, 256, 0, stream>>>(hq, hd, out);
    colbert_loss<<<1, 256, 0, stream>>>(out, out + NQ * MD);
}